// Round 1
// baseline (670.429 us; speedup 1.0000x reference)
//
#include <hip/hip_runtime.h>

// GCN: out = D^-1/2 (A+I) D^-1/2 X W + b, twice, then mean-pool + FC + log_softmax.
// Sizes: N=100000 nodes, E=3200000 edges, G=512 graphs, F: 64 -> 16 -> 16 -> 2.

__global__ void deg_kernel(const int* __restrict__ col, const float* __restrict__ ew,
                           float* __restrict__ deg, int E) {
    int t = blockIdx.x * blockDim.x + threadIdx.x;
    if (t < E) atomicAdd(&deg[col[t]], ew[t]);
}

// deg -> dinv in place (self-loop adds +1, so deg+1 >= 1 > 0 always)
__global__ void dinv_kernel(float* __restrict__ deg, int N) {
    int i = blockIdx.x * blockDim.x + threadIdx.x;
    if (i < N) deg[i] = rsqrtf(deg[i] + 1.0f);
}

// xw = x @ W1   (N x 64) @ (64 x 16), one thread per node row
__global__ void gemm1_kernel(const float* __restrict__ x, const float* __restrict__ W1,
                             float* __restrict__ xw, int N) {
    __shared__ float Ws[64 * 16];
    for (int k = threadIdx.x; k < 64 * 16; k += blockDim.x) Ws[k] = W1[k];
    __syncthreads();
    int i = blockIdx.x * blockDim.x + threadIdx.x;
    if (i >= N) return;
    const float4* xp = reinterpret_cast<const float4*>(x + (size_t)i * 64);
    float acc[16];
#pragma unroll
    for (int j = 0; j < 16; ++j) acc[j] = 0.0f;
#pragma unroll
    for (int k4 = 0; k4 < 16; ++k4) {
        float4 xv = xp[k4];
#pragma unroll
        for (int j = 0; j < 16; ++j) {
            acc[j] += xv.x * Ws[(k4 * 4 + 0) * 16 + j]
                    + xv.y * Ws[(k4 * 4 + 1) * 16 + j]
                    + xv.z * Ws[(k4 * 4 + 2) * 16 + j]
                    + xv.w * Ws[(k4 * 4 + 3) * 16 + j];
        }
    }
    float4* op = reinterpret_cast<float4*>(xw + (size_t)i * 16);
    op[0] = make_float4(acc[0],  acc[1],  acc[2],  acc[3]);
    op[1] = make_float4(acc[4],  acc[5],  acc[6],  acc[7]);
    op[2] = make_float4(acc[8],  acc[9],  acc[10], acc[11]);
    op[3] = make_float4(acc[12], acc[13], acc[14], acc[15]);
}

// out[i][j] = dinv[i]^2 * xw[i][j]   (self-loop term; initializes out, no memset needed)
__global__ void selfloop_kernel(const float* __restrict__ xw, const float* __restrict__ dinv,
                                float* __restrict__ out, int N) {
    int t = blockIdx.x * blockDim.x + threadIdx.x;
    if (t >= N * 16) return;
    int i = t >> 4;
    float d = dinv[i];
    out[t] = d * d * xw[t];
}

// one thread per (edge, feature): out[col][j] += dinv[row]*ew*dinv[col] * xw[row][j]
__global__ void edge_kernel(const int* __restrict__ row, const int* __restrict__ col,
                            const float* __restrict__ ew, const float* __restrict__ dinv,
                            const float* __restrict__ xw, float* __restrict__ out, int E) {
    int t = blockIdx.x * blockDim.x + threadIdx.x;
    if (t >= E * 16) return;
    int e = t >> 4, j = t & 15;
    int r = row[e], c = col[e];
    float norm = dinv[r] * ew[e] * dinv[c];
    atomicAdd(&out[c * 16 + j], norm * xw[r * 16 + j]);
}

// xw2 = relu(in + b) @ W2   (N x 16) @ (16 x 16), one thread per node row
__global__ void gemm2_kernel(const float* __restrict__ in, const float* __restrict__ b,
                             const float* __restrict__ W, float* __restrict__ xw, int N) {
    __shared__ float Ws[16 * 16];
    __shared__ float bs[16];
    if (threadIdx.x < 16 * 16) Ws[threadIdx.x] = W[threadIdx.x];
    if (threadIdx.x < 16) bs[threadIdx.x] = b[threadIdx.x];
    __syncthreads();
    int i = blockIdx.x * blockDim.x + threadIdx.x;
    if (i >= N) return;
    const float4* ip = reinterpret_cast<const float4*>(in + (size_t)i * 16);
    float h[16];
#pragma unroll
    for (int q = 0; q < 4; ++q) {
        float4 v = ip[q];
        h[q * 4 + 0] = fmaxf(v.x + bs[q * 4 + 0], 0.0f);
        h[q * 4 + 1] = fmaxf(v.y + bs[q * 4 + 1], 0.0f);
        h[q * 4 + 2] = fmaxf(v.z + bs[q * 4 + 2], 0.0f);
        h[q * 4 + 3] = fmaxf(v.w + bs[q * 4 + 3], 0.0f);
    }
    float acc[16];
#pragma unroll
    for (int j = 0; j < 16; ++j) acc[j] = 0.0f;
#pragma unroll
    for (int k = 0; k < 16; ++k) {
#pragma unroll
        for (int j = 0; j < 16; ++j) acc[j] += h[k] * Ws[k * 16 + j];
    }
    float4* op = reinterpret_cast<float4*>(xw + (size_t)i * 16);
    op[0] = make_float4(acc[0],  acc[1],  acc[2],  acc[3]);
    op[1] = make_float4(acc[4],  acc[5],  acc[6],  acc[7]);
    op[2] = make_float4(acc[8],  acc[9],  acc[10], acc[11]);
    op[3] = make_float4(acc[12], acc[13], acc[14], acc[15]);
}

// pooled[g][j] += relu(out2[i][j] + b2[j]); cnt[g] += 1 (once per node)
__global__ void pool_kernel(const float* __restrict__ out2, const float* __restrict__ b2,
                            const int* __restrict__ batch, float* __restrict__ pooled,
                            float* __restrict__ cnt, int N) {
    int t = blockIdx.x * blockDim.x + threadIdx.x;
    if (t >= N * 16) return;
    int i = t >> 4, j = t & 15;
    float v = fmaxf(out2[t] + b2[j], 0.0f);
    int g = batch[i];
    atomicAdd(&pooled[g * 16 + j], v);
    if (j == 0) atomicAdd(&cnt[g], 1.0f);
}

// logits = (pooled/cnt) @ Wfc + bfc ; out = log_softmax(logits) over 2 classes
__global__ void head_kernel(const float* __restrict__ pooled, const float* __restrict__ cnt,
                            const float* __restrict__ Wfc, const float* __restrict__ bfc,
                            float* __restrict__ out, int G) {
    int g = blockIdx.x * blockDim.x + threadIdx.x;
    if (g >= G) return;
    float c = fmaxf(cnt[g], 1.0f);
    float l0 = bfc[0], l1 = bfc[1];
#pragma unroll
    for (int j = 0; j < 16; ++j) {
        float p = pooled[g * 16 + j] / c;
        l0 += p * Wfc[j * 2 + 0];
        l1 += p * Wfc[j * 2 + 1];
    }
    float m = fmaxf(l0, l1);
    float lse = m + logf(expf(l0 - m) + expf(l1 - m));
    out[g * 2 + 0] = l0 - lse;
    out[g * 2 + 1] = l1 - lse;
}

extern "C" void kernel_launch(void* const* d_in, const int* in_sizes, int n_in,
                              void* d_out, int out_size, void* d_ws, size_t ws_size,
                              hipStream_t stream) {
    const float* x   = (const float*)d_in[0];
    const int*   ei  = (const int*)d_in[1];
    const float* ew  = (const float*)d_in[2];
    const int*   bat = (const int*)d_in[3];
    const float* W1  = (const float*)d_in[4];
    const float* b1  = (const float*)d_in[5];
    const float* W2  = (const float*)d_in[6];
    const float* b2  = (const float*)d_in[7];
    const float* Wfc = (const float*)d_in[8];
    const float* bfc = (const float*)d_in[9];
    float* out = (float*)d_out;

    const int N = in_sizes[0] / 64;   // 100000
    const int E = in_sizes[2];        // 3200000
    const int G = out_size / 2;       // 512

    const int* row = ei;
    const int* col = ei + E;

    // workspace layout (floats)
    float* ws     = (float*)d_ws;
    float* dinv   = ws;                 // N      (deg, then dinv in place)
    float* xw1    = dinv + N;           // N*16
    float* out1   = xw1 + (size_t)N * 16;   // N*16
    float* xw2    = out1 + (size_t)N * 16;  // N*16
    float* out2   = xw2 + (size_t)N * 16;   // N*16
    float* pooled = out2 + (size_t)N * 16;  // G*16
    float* cnt    = pooled + (size_t)G * 16; // G

    hipMemsetAsync(dinv, 0, (size_t)N * sizeof(float), stream);
    hipMemsetAsync(pooled, 0, (size_t)(G * 16 + G) * sizeof(float), stream);

    const int B = 256;
    const int nbN   = (N + B - 1) / B;
    const int nbN16 = (N * 16 + B - 1) / B;
    const int nbE   = (E + B - 1) / B;
    const int nbE16 = (int)(((long long)E * 16 + B - 1) / B);

    deg_kernel<<<nbE, B, 0, stream>>>(col, ew, dinv, E);
    dinv_kernel<<<nbN, B, 0, stream>>>(dinv, N);

    gemm1_kernel<<<nbN, B, 0, stream>>>(x, W1, xw1, N);
    selfloop_kernel<<<nbN16, B, 0, stream>>>(xw1, dinv, out1, N);
    edge_kernel<<<nbE16, B, 0, stream>>>(row, col, ew, dinv, xw1, out1, E);

    gemm2_kernel<<<nbN, B, 0, stream>>>(out1, b1, W2, xw2, N);
    selfloop_kernel<<<nbN16, B, 0, stream>>>(xw2, dinv, out2, N);
    edge_kernel<<<nbE16, B, 0, stream>>>(row, col, ew, dinv, xw2, out2, E);

    pool_kernel<<<nbN16, B, 0, stream>>>(out2, b2, bat, pooled, cnt, N);
    head_kernel<<<(G + B - 1) / B, B, 0, stream>>>(pooled, cnt, Wfc, bfc, out, G);
}